// Round 3
// baseline (146.744 us; speedup 1.0000x reference)
//
#include <hip/hip_runtime.h>

// Problem constants (fixed by the reference setup_inputs):
//   input_tensor: [8, 128, 128, 128, 1] fp32
//   random_u:     [8, 8, 3] fp32
//   SCALE = 0.2
#define NB   8
#define NS   128          // D = H = W = 128
#define VOXELS_PER_B (NS*NS*NS)   // 2^21

// ---------------------------------------------------------------------------
// Fused kernel: per-block affine solve (A^T A = 8*I -> closed form) + grid
// warp + trilinear resample. Thread-coarsened x4 along d so lanes stay dense
// along w (gather lane-stride ~0.9 elements -> ~4 cache lines per wave load
// instead of ~15 with w-coarsening: L1 pipe is the bottleneck).
// ---------------------------------------------------------------------------
__global__ __launch_bounds__(256) void warp_resample_kernel(
        const float* __restrict__ img, const float* __restrict__ u,
        float* __restrict__ out) {
    int tid = threadIdx.x;
    int gid = blockIdx.x * 256 + tid;
    int w    = gid & (NS - 1);          // lanes dense along w
    int h    = (gid >> 7) & (NS - 1);   // block covers 2 h-rows
    int dblk = (gid >> 14) & 31;        // 4 d's per thread
    int b    = blockIdx.x >> 11;        // uniform per block

    // --- affine transform from noise, computed redundantly per block ---
    // transform[i][j] = (1/8) sum_n c_n[j] * c_n[i] * s_n[i]   (j<3)
    // transform[i][3] = (1/8) sum_n        c_n[i] * s_n[i]
    // with c_n[m] = +-1 from bit (2-m) of n, s_n[i] = 0.8 + 0.2*u[b][n][i].
    __shared__ float t[12];
    if (tid < 12) {
        int i = tid >> 2;               // row 0..2
        int j = tid & 3;                // col 0..3
        float acc = 0.0f;
#pragma unroll
        for (int n = 0; n < 8; ++n) {
            float ci = (n & (4 >> i)) ? 1.0f : -1.0f;
            float cj = (j < 3) ? ((n & (4 >> j)) ? 1.0f : -1.0f) : 1.0f;
            float s  = 0.8f + 0.2f * u[(b * 8 + n) * 3 + i];
            acc += cj * ci * s;
        }
        t[tid] = acc * 0.125f;
    }
    __syncthreads();

    const float inv = 2.0f / 127.0f;    // linspace(-1,1,128) step
    int   d0 = dblk << 2;
    float x  = -1.0f + d0 * inv;
    float y  = -1.0f + h * inv;
    float z  = -1.0f + w * inv;

    // pixel coords; per-d step of q_i is exactly t[i*4] (inv*63.5 == 1)
    float q0 = (t[0] * x + t[1] * y + t[2]  * z + t[3]  + 1.0f) * 63.5f;
    float q1 = (t[4] * x + t[5] * y + t[6]  * z + t[7]  + 1.0f) * 63.5f;
    float q2 = (t[8] * x + t[9] * y + t[10] * z + t[11] + 1.0f) * 63.5f;
    float dq0 = t[0], dq1 = t[4], dq2 = t[8];

    int   i0[4], i1[4], i2[4];
    float r0[4], r1[4], r2[4];
    bool  allok = true;
#pragma unroll
    for (int k = 0; k < 4; ++k) {
        float f0 = floorf(q0), f1 = floorf(q1), f2 = floorf(q2);
        i0[k] = (int)f0; i1[k] = (int)f1; i2[k] = (int)f2;
        r0[k] = q0 - f0; r1[k] = q1 - f1; r2[k] = q2 - f2;
        allok = allok && ((unsigned)i0[k] < 127u) &&
                         ((unsigned)i1[k] < 127u) &&
                         ((unsigned)i2[k] < 127u);
        q0 += dq0; q1 += dq1; q2 += dq2;
    }

    const float* __restrict__ base = img + (size_t)b * VOXELS_PER_B;
    float res[4];

    if (__all(allok)) {
        // interior: no clamping; one base pointer + immediate offsets per k.
        // All 32 loads sit in one branch-free region -> batched under vmcnt.
#pragma unroll
        for (int k = 0; k < 4; ++k) {
            const float* p = base + (((i0[k] << 7) + i1[k]) << 7) + i2[k];
            float v000 = p[0],            v001 = p[1];
            float v010 = p[NS],           v011 = p[NS + 1];
            float v100 = p[NS * NS],      v101 = p[NS * NS + 1];
            float v110 = p[NS * NS + NS], v111 = p[NS * NS + NS + 1];
            float a0 = v000 + r2[k] * (v001 - v000);
            float a1 = v010 + r2[k] * (v011 - v010);
            float a2 = v100 + r2[k] * (v101 - v100);
            float a3 = v110 + r2[k] * (v111 - v110);
            float b0 = a0 + r1[k] * (a1 - a0);
            float b1 = a2 + r1[k] * (a3 - a2);
            res[k] = b0 + r0[k] * (b1 - b0);
        }
    } else {
        // boundary: reference semantics (clip indices, zero weights)
#pragma unroll
        for (int k = 0; k < 4; ++k) {
            float wd0 = (i0[k] >= 0     && i0[k] < NS)     ? (1.0f - r0[k]) : 0.0f;
            float wd1 = (i0[k] + 1 >= 0 && i0[k] + 1 < NS) ? r0[k]          : 0.0f;
            float wh0 = (i1[k] >= 0     && i1[k] < NS)     ? (1.0f - r1[k]) : 0.0f;
            float wh1 = (i1[k] + 1 >= 0 && i1[k] + 1 < NS) ? r1[k]          : 0.0f;
            float ww0 = (i2[k] >= 0     && i2[k] < NS)     ? (1.0f - r2[k]) : 0.0f;
            float ww1 = (i2[k] + 1 >= 0 && i2[k] + 1 < NS) ? r2[k]          : 0.0f;

            int cd0 = min(max(i0[k],     0), NS - 1);
            int cd1 = min(max(i0[k] + 1, 0), NS - 1);
            int ch0 = min(max(i1[k],     0), NS - 1);
            int ch1 = min(max(i1[k] + 1, 0), NS - 1);
            int cw0 = min(max(i2[k],     0), NS - 1);
            int cw1 = min(max(i2[k] + 1, 0), NS - 1);

            int r00 = (cd0 * NS + ch0) * NS;
            int r01 = (cd0 * NS + ch1) * NS;
            int r10 = (cd1 * NS + ch0) * NS;
            int r11 = (cd1 * NS + ch1) * NS;

            float v000 = base[r00 + cw0], v001 = base[r00 + cw1];
            float v010 = base[r01 + cw0], v011 = base[r01 + cw1];
            float v100 = base[r10 + cw0], v101 = base[r10 + cw1];
            float v110 = base[r11 + cw0], v111 = base[r11 + cw1];

            res[k] = v000 * (wd0 * wh0 * ww0)
                   + v001 * (wd0 * wh0 * ww1)
                   + v010 * (wd0 * wh1 * ww0)
                   + v011 * (wd0 * wh1 * ww1)
                   + v100 * (wd1 * wh0 * ww0)
                   + v101 * (wd1 * wh0 * ww1)
                   + v110 * (wd1 * wh1 * ww0)
                   + v111 * (wd1 * wh1 * ww1);
        }
    }

    // stores: lanes consecutive in w -> coalesced dword stores, one per d
    int obase = (((b << 7) + d0) << 14) + (h << 7) + w;
#pragma unroll
    for (int k = 0; k < 4; ++k)
        out[obase + (k << 14)] = res[k];
}

extern "C" void kernel_launch(void* const* d_in, const int* in_sizes, int n_in,
                              void* d_out, int out_size, void* d_ws, size_t ws_size,
                              hipStream_t stream) {
    const float* img = (const float*)d_in[0];   // [8,128,128,128,1] fp32
    const float* u   = (const float*)d_in[1];   // [8,8,3] fp32
    float* out = (float*)d_out;

    int total   = NB * VOXELS_PER_B;            // 16,777,216
    int threads = total / 4;                    // 4 outputs (along d) per thread
    int blocks  = threads / 256;                // 16,384
    warp_resample_kernel<<<blocks, 256, 0, stream>>>(img, u, out);
}

// Round 4
// 130.702 us; speedup vs baseline: 1.1227x; 1.1227x over previous
//
#include <hip/hip_runtime.h>

// input_tensor: [8,128,128,128,1] fp32 ; random_u: [8,8,3] fp32 ; SCALE=0.2
#define NB   8
#define NS   128
#define VOX  (NS*NS*NS)

// Slab geometry (worst-case provable: |t_offdiag| <= 0.1, t_diag in [0.8,1]):
// tile 32w x 8h x 4d ->
//   p0 span <= 3*1 + 7*0.1 + 31*0.1 = 6.8  -> d rows  <= 7+4  = 11
//   p1 span <= 7*1 + 3*0.1 + 31*0.1 = 10.4 -> h rows  <= 11+4 = 15
//   p2 span <= 31*1+ 3*0.1 + 7*0.1  = 32.0 -> w window <= 39  -> 40 (10x dwordx4)
#define DS_D  11
#define DS_H  15
#define ROW_W 40

typedef __attribute__((address_space(1))) const void gconst_t;
typedef __attribute__((address_space(3))) void lds_t;

__global__ __launch_bounds__(256) void warp_resample_kernel(
        const float* __restrict__ img, const float* __restrict__ u,
        float* __restrict__ out) {
    __shared__ __align__(16) float tm[12];
    __shared__ __align__(16) float slab[DS_D * DS_H * ROW_W + 8];

    const int tid  = threadIdx.x;
    const int bi   = blockIdx.x;
    const int wblk =  bi       & 3;    // 4 w-tiles
    const int hblk = (bi >> 2) & 15;   // 16 h-tiles
    const int dblk = (bi >> 6) & 31;   // 32 d-tiles
    const int b    =  bi >> 11;        // 8 batches

    // ---- affine transform from noise (A^T A = 8I -> closed form), 12 lanes ----
    if (tid < 12) {
        int i = tid >> 2, j = tid & 3;
        float acc = 0.f;
#pragma unroll
        for (int n = 0; n < 8; ++n) {
            float ci = (n & (4 >> i)) ? 1.f : -1.f;
            float cj = (j < 3) ? ((n & (4 >> j)) ? 1.f : -1.f) : 1.f;
            float s  = 0.8f + 0.2f * u[(b * 8 + n) * 3 + i];
            acc += cj * ci * s;
        }
        tm[tid] = acc * 0.125f;
    }
    __syncthreads();

    const float4 T0 = *(const float4*)&tm[0];
    const float4 T1 = *(const float4*)&tm[4];
    const float4 T2 = *(const float4*)&tm[8];

    const int d0 = dblk << 2, h0 = hblk << 3, w0 = wblk << 5;
    const float inv = 2.0f / 127.0f;
    // pixel-space q at tile origin; per-index pixel delta == t (inv*63.5 == 1)
    const float x0 = -1.f + d0 * inv, y0 = -1.f + h0 * inv, z0 = -1.f + w0 * inv;
    const float P0 = (T0.x * x0 + T0.y * y0 + T0.z * z0 + T0.w + 1.f) * 63.5f;
    const float P1 = (T1.x * x0 + T1.y * y0 + T1.z * z0 + T1.w + 1.f) * 63.5f;
    const float P2 = (T2.x * x0 + T2.y * y0 + T2.z * z0 + T2.w + 1.f) * 63.5f;

    // tile bounds via corner extremes (kd<=3, kh<=7, kw<=31)
    float mn0 = P0 + fminf(0.f, 3.f*T0.x) + fminf(0.f, 7.f*T0.y) + fminf(0.f, 31.f*T0.z);
    float mx0 = P0 + fmaxf(0.f, 3.f*T0.x) + fmaxf(0.f, 7.f*T0.y) + fmaxf(0.f, 31.f*T0.z);
    float mn1 = P1 + fminf(0.f, 3.f*T1.x) + fminf(0.f, 7.f*T1.y) + fminf(0.f, 31.f*T1.z);
    float mx1 = P1 + fmaxf(0.f, 3.f*T1.x) + fmaxf(0.f, 7.f*T1.y) + fmaxf(0.f, 31.f*T1.z);
    float mn2 = P2 + fminf(0.f, 3.f*T2.x) + fminf(0.f, 7.f*T2.y) + fminf(0.f, 31.f*T2.z);
    float mx2 = P2 + fmaxf(0.f, 3.f*T2.x) + fmaxf(0.f, 7.f*T2.y) + fmaxf(0.f, 31.f*T2.z);

    const int i0mn = (int)floorf(mn0), i0mx = (int)floorf(mx0);
    const int i1mn = (int)floorf(mn1), i1mx = (int)floorf(mx1);
    const int i2mn = (int)floorf(mn2), i2mx = (int)floorf(mx2);

    const int d_lo = min(max(i0mn - 1, 0), NS - 1);
    const int d_hi = min(max(i0mx + 2, 0), NS - 1);
    const int h_lo = min(max(i1mn - 1, 0), NS - 1);
    const int h_hi = min(max(i1mx + 2, 0), NS - 1);
    const int Sd   = min(d_hi - d_lo + 1, DS_D);
    const int Sh   = min(h_hi - h_lo + 1, DS_H);
    const int ws   = min(max((i2mn - 1) & ~3, 0), NS - ROW_W);

    const bool interior = (i0mn >= 1) && (i0mx <= 125) &&
                          (i1mn >= 1) && (i1mx <= 125) &&
                          (i2mn >= 1) && (i2mx <= 125);

    // ---- stage slab: Sd*Sh rows of ROW_W floats via global_load_lds x16 ----
    // task tid -> (hi = tid/10, chunk = tid%10); lds float-offset = 4*tid, so
    // wave base = di*Sh*ROW_W + 256*wave  (lane-contiguous packing, 16B aligned)
    {
        const float* gb = img + (size_t)b * VOX;
        int hi = tid / 10;
        int c  = tid - hi * 10;
        bool active = (hi < Sh);
        int wvbase = (tid & ~63) << 2;                     // floats
        for (int di = 0; di < Sd; ++di) {
            if (active) {
                const float* g = gb + (((d_lo + di) * NS + (h_lo + hi)) * NS + ws + (c << 2));
                __builtin_amdgcn_global_load_lds(
                    (gconst_t*)g,
                    (lds_t*)(slab + di * Sh * ROW_W + wvbase),
                    16, 0, 0);
            }
        }
    }
    __syncthreads();

    // ---- compute: thread = (wg 0..7, hh 0..7, dd 0..3); 4 voxels along w ----
    const int wg = tid & 7, hh = (tid >> 3) & 7, dd = tid >> 6;
    const int d = d0 + dd, h = h0 + hh, wbase = w0 + (wg << 2);

    float q0 = P0 + dd * T0.x + hh * T0.y + (float)(wg << 2) * T0.z;
    float q1 = P1 + dd * T1.x + hh * T1.y + (float)(wg << 2) * T1.z;
    float q2 = P2 + dd * T2.x + hh * T2.y + (float)(wg << 2) * T2.z;

    const int rstride = Sh * ROW_W;
    float res[4];

    if (interior) {
#pragma unroll
        for (int k = 0; k < 4; ++k) {
            float f0 = floorf(q0), f1 = floorf(q1), f2 = floorf(q2);
            int   i0 = (int)f0,    i1 = (int)f1,    i2 = (int)f2;
            float r0 = q0 - f0,    r1 = q1 - f1,    r2 = q2 - f2;

            int base = (i0 - d_lo) * rstride + (i1 - h_lo) * ROW_W + (i2 - ws);
            float a00 = slab[base],              b00 = slab[base + 1];
            float a01 = slab[base + ROW_W],      b01 = slab[base + ROW_W + 1];
            int base2 = base + rstride;
            float a10 = slab[base2],             b10 = slab[base2 + 1];
            float a11 = slab[base2 + ROW_W],     b11 = slab[base2 + ROW_W + 1];

            float e0 = fmaf(r2, b00 - a00, a00);
            float e1 = fmaf(r2, b01 - a01, a01);
            float e2 = fmaf(r2, b10 - a10, a10);
            float e3 = fmaf(r2, b11 - a11, a11);
            float c0 = fmaf(r1, e1 - e0, e0);
            float c1 = fmaf(r1, e3 - e2, e2);
            res[k] = fmaf(r0, c1 - c0, c0);

            q0 += T0.z; q1 += T1.z; q2 += T2.z;
        }
    } else {
        // boundary: clip indices, zero weights (reference semantics), all
        // reads provably inside the staged window
#pragma unroll
        for (int k = 0; k < 4; ++k) {
            float f0 = floorf(q0), f1 = floorf(q1), f2 = floorf(q2);
            int   i0 = (int)f0,    i1 = (int)f1,    i2 = (int)f2;
            float r0 = q0 - f0,    r1 = q1 - f1,    r2 = q2 - f2;

            float wd0 = (i0 >= 0     && i0 < NS)     ? (1.0f - r0) : 0.0f;
            float wd1 = (i0 + 1 < NS)                ? r0          : 0.0f;
            float wh0 = (i1 >= 0     && i1 < NS)     ? (1.0f - r1) : 0.0f;
            float wh1 = (i1 + 1 < NS)                ? r1          : 0.0f;
            float ww0 = (i2 >= 0     && i2 < NS)     ? (1.0f - r2) : 0.0f;
            float ww1 = (i2 + 1 >= 0 && i2 + 1 < NS) ? r2          : 0.0f;

            int cw0 = min(max(i2,     0), NS - 1);
            int cw1 = min(max(i2 + 1, 0), NS - 1);
            int dI0 = min(max(min(max(i0,     0), NS - 1) - d_lo, 0), Sd - 1);
            int dI1 = min(max(min(max(i0 + 1, 0), NS - 1) - d_lo, 0), Sd - 1);
            int hI0 = min(max(min(max(i1,     0), NS - 1) - h_lo, 0), Sh - 1);
            int hI1 = min(max(min(max(i1 + 1, 0), NS - 1) - h_lo, 0), Sh - 1);
            int j0  = min(max(cw0 - ws, 0), ROW_W - 1);
            bool same = (cw1 == cw0);

            float acc = 0.f;
            {
                int bb = dI0 * rstride + hI0 * ROW_W + j0;
                float a = slab[bb], bv = slab[bb + 1];
                float rt = same ? a : bv;
                acc = fmaf(fmaf(a, ww0, rt * ww1), wd0 * wh0, acc);
            }
            {
                int bb = dI0 * rstride + hI1 * ROW_W + j0;
                float a = slab[bb], bv = slab[bb + 1];
                float rt = same ? a : bv;
                acc = fmaf(fmaf(a, ww0, rt * ww1), wd0 * wh1, acc);
            }
            {
                int bb = dI1 * rstride + hI0 * ROW_W + j0;
                float a = slab[bb], bv = slab[bb + 1];
                float rt = same ? a : bv;
                acc = fmaf(fmaf(a, ww0, rt * ww1), wd1 * wh0, acc);
            }
            {
                int bb = dI1 * rstride + hI1 * ROW_W + j0;
                float a = slab[bb], bv = slab[bb + 1];
                float rt = same ? a : bv;
                acc = fmaf(fmaf(a, ww0, rt * ww1), wd1 * wh1, acc);
            }
            res[k] = acc;

            q0 += T0.z; q1 += T1.z; q2 += T2.z;
        }
    }

    size_t oidx = (((size_t)(b * NS + d) * NS + h) * NS) + wbase;
    *reinterpret_cast<float4*>(out + oidx) =
        make_float4(res[0], res[1], res[2], res[3]);
}

extern "C" void kernel_launch(void* const* d_in, const int* in_sizes, int n_in,
                              void* d_out, int out_size, void* d_ws, size_t ws_size,
                              hipStream_t stream) {
    const float* img = (const float*)d_in[0];   // [8,128,128,128,1] fp32
    const float* u   = (const float*)d_in[1];   // [8,8,3] fp32
    float* out = (float*)d_out;

    int blocks = NB * 32 * 16 * 4;              // 16,384 (4w x 16h x 32d tiles)
    warp_resample_kernel<<<blocks, 256, 0, stream>>>(img, u, out);
}